// Round 7
// baseline (279.943 us; speedup 1.0000x reference)
//
#include <hip/hip_runtime.h>
#include <hip/hip_bf16.h>

typedef __hip_bfloat16 bf16;
typedef unsigned int uint;
typedef unsigned short ushort;

using frag8 = __attribute__((ext_vector_type(8))) short;   // 8 bf16
using f32x4 = __attribute__((ext_vector_type(4))) float;
using f32x2 = __attribute__((ext_vector_type(2))) float;

#define HWH 784   // 28*28

// ---------------------------------------------------------------------------
// Fold fc_w (9x12) into dep_w (256,9,3,3):  W2[oc][c12][k9]; also biascat.
// ---------------------------------------------------------------------------
__global__ __launch_bounds__(256) void fold_w2(const float* __restrict__ fc_w,
                                               const float* __restrict__ dep_w,
                                               const float* __restrict__ b1,
                                               const float* __restrict__ b2,
                                               const float* __restrict__ b3,
                                               float* __restrict__ W2,
                                               float* __restrict__ biascat) {
    int idx = blockIdx.x * 256 + threadIdx.x;   // oc*108 + c12*9 + k9
    if (idx < 768) {
        const float* bs = idx < 256 ? b1 : (idx < 512 ? b2 : b3);
        biascat[idx] = bs[idx & 255];
    }
    if (idx >= 256 * 108) return;
    int oc  = idx / 108;
    int r   = idx % 108;
    int c12 = r / 9;
    int k9  = r % 9;
    float s = 0.f;
#pragma unroll
    for (int o = 0; o < 9; ++o)
        s += fc_w[o * 12 + c12] * dep_w[oc * 81 + o * 9 + k9];
    W2[idx] = s;
}

// ---------------------------------------------------------------------------
// Weights f32 -> bf16, concatenated [768][256] (q:w1, k:w2, v:w3)
// ---------------------------------------------------------------------------
__global__ __launch_bounds__(256) void wprep(const float* __restrict__ w1,
                                             const float* __restrict__ w2,
                                             const float* __restrict__ w3,
                                             bf16* __restrict__ wbf) {
    int row = blockIdx.x, tid = threadIdx.x;
    const float* src = row < 256 ? w1 : (row < 512 ? w2 : w3);
    wbf[row * 256 + tid] = __float2bfloat16(src[(row & 255) * 256 + tid]);
}

// ---------------------------------------------------------------------------
// x [b][c=256][n=784] f32  ->  xT [b][n=784][c=256] bf16  (32x32 LDS tiles)
// ---------------------------------------------------------------------------
__global__ __launch_bounds__(256) void xpose(const float* __restrict__ x,
                                             bf16* __restrict__ xT) {
    __shared__ float t[32][33];
    const int n0 = blockIdx.x * 32, c0 = blockIdx.y * 32, b = blockIdx.z;
    const int tid = threadIdx.x;
    const float* xb = x + (size_t)b * (256 * HWH);
#pragma unroll
    for (int e = tid; e < 1024; e += 256) {
        int r = e >> 5, col = e & 31;           // r: c-index, col: n-index
        int n = n0 + col;
        t[r][col] = (n < HWH) ? xb[(size_t)(c0 + r) * HWH + n] : 0.f;
    }
    __syncthreads();
#pragma unroll
    for (int e = tid; e < 512; e += 256) {
        int r = e >> 4, cp = (e & 15) * 2;      // r: n-index, cp: c-pair
        int n = n0 + r;
        if (n < HWH) {
            __hip_bfloat162 h;
            h.x = __float2bfloat16(t[cp][r]);
            h.y = __float2bfloat16(t[cp + 1][r]);
            *reinterpret_cast<__hip_bfloat162*>(
                &xT[((size_t)b * HWH + n) * 256 + c0 + cp]) = h;
        }
    }
}

// ---------------------------------------------------------------------------
// MFMA GEMM (R7): 256x128 tile, 3 m-tiles, 1-D XCD-aligned grid.
// perm[b][g][t][n] = sum_k wbf[m][k]*xT[b][n][k] + bias[m];
// m -> sec=m/256, ch=m%256: plane index t=sec*4+ch/64, group g=ch%64.
// 4 waves, each 64(rows)x128(cols) = 4x8 frags of 16x16x32 bf16 MFMA.
// lin = m*448 + (b*7+n): same (b,n) across m => 448 apart => same XCD => L2 reuse.
// ---------------------------------------------------------------------------
__device__ inline void load_lds16(const bf16* g, short* lds) {
    __builtin_amdgcn_global_load_lds(
        (const __attribute__((address_space(1))) void*)g,
        (__attribute__((address_space(3))) void*)lds, 16, 0, 0);
}

__global__ __launch_bounds__(256) void gemm_mfma2(const bf16* __restrict__ wbf,
                                                  const float* __restrict__ biascat,
                                                  const bf16* __restrict__ xT,
                                                  bf16* __restrict__ perm) {
    __shared__ short lds[12288];   // A: [0,8192) = 16 blocks; B: [8192,12288) = 8 blocks

    const int tid  = threadIdx.x;
    const int wave = tid >> 6, lane = tid & 63;
    const int lin  = blockIdx.x;
    const int mt   = lin / 448;                 // m-tile 0..2
    const int rem  = lin - mt * 448;
    const int b    = rem / 7;
    const int nt   = rem - b * 7;
    const int m0   = mt * 256;
    const int n0   = nt * 128;
    const int lrow = lane & 15, lkc = lane >> 4;

    f32x4 acc[4][8] = {};
    const bf16* xb = xT + (size_t)b * (HWH * 256);

    for (int k0 = 0; k0 < 256; k0 += 32) {
#pragma unroll
        for (int i = 0; i < 4; ++i) {           // A: 4 blocks per wave (16 total)
            const int jb = 4 * wave + i;
            const bf16* ga = wbf + (size_t)(m0 + 16 * jb + lrow) * 256 + k0 + lkc * 8;
            load_lds16(ga, &lds[jb * 512]);
        }
#pragma unroll
        for (int i = 0; i < 2; ++i) {           // B: 2 blocks per wave (8 total)
            const int jb = 2 * wave + i;
            int n = n0 + 16 * jb + lrow;
            if (n > HWH - 1) n = HWH - 1;       // clamp: OOB cols never stored
            const bf16* gb = xb + (size_t)n * 256 + k0 + lkc * 8;
            load_lds16(gb, &lds[8192 + jb * 512]);
        }
        __syncthreads();

        frag8 af[4], bf_[8];
#pragma unroll
        for (int i = 0; i < 4; ++i)
            af[i] = *reinterpret_cast<const frag8*>(&lds[(4 * wave + i) * 512 + lane * 8]);
#pragma unroll
        for (int j = 0; j < 8; ++j)
            bf_[j] = *reinterpret_cast<const frag8*>(&lds[8192 + j * 512 + lane * 8]);
#pragma unroll
        for (int i = 0; i < 4; ++i)
#pragma unroll
            for (int j = 0; j < 8; ++j)
                acc[i][j] = __builtin_amdgcn_mfma_f32_16x16x32_bf16(
                    af[i], bf_[j], acc[i][j], 0, 0, 0);
        __syncthreads();
    }

    // Epilogue: C/D layout col=lane&15 (n), row=(lane>>4)*4+reg (m)
#pragma unroll
    for (int i = 0; i < 4; ++i) {
        const int rowb = m0 + wave * 64 + i * 16 + lkc * 4;
        bf16* dsts[4]; float bias4[4];
#pragma unroll
        for (int r = 0; r < 4; ++r) {
            const int m = rowb + r;
            const int sec = m >> 8, ch = m & 255;
            dsts[r] = perm + (((size_t)b * 64 + (ch & 63)) * 12 + sec * 4 + (ch >> 6)) * HWH;
            bias4[r] = biascat[m];
        }
#pragma unroll
        for (int j = 0; j < 8; ++j) {
            const int col = n0 + j * 16 + lrow;
            if (col < HWH) {
#pragma unroll
                for (int r = 0; r < 4; ++r)
                    dsts[r][col] = __float2bfloat16(acc[i][j][r] + bias4[r]);
            }
        }
    }
}

// ---------------------------------------------------------------------------
// Fused output: out = rate1 * att + rate2 * conv.
// R7 change: phase C uses f32x2 packed math (v_pk_fma_f32) — even-pair taps
// vectorize naturally; per-element accumulation order unchanged.
// ---------------------------------------------------------------------------
__global__ __launch_bounds__(256) void out_fused5(
    const bf16* __restrict__ perm, const float* __restrict__ W2,
    const float* __restrict__ rate1, const float* __restrict__ rate2,
    float* __restrict__ out) {
    __shared__ __align__(16) short plane[12][1020];  // 30 rows x pitch 34, 1-halo
    __shared__ float w2s2[4][12][12];                // [oc][c][k], k padded 9->12
    __shared__ float attb[4][49];
    __shared__ __align__(16) short vatt[4][784];

    const int g = blockIdx.x, b = blockIdx.y, tid = threadIdx.x;

    // ---- phase A: LDS fill ----
    for (int e = tid; e < 576; e += 256) {      // weights, float4-friendly layout
        int oc = e / 144, rem = e % 144, c = rem / 12, k = rem % 12;
        w2s2[oc][c][k] = (k < 9) ? W2[(4 * g + oc) * 108 + c * 9 + k] : 0.f;
    }
    if (tid < 196) attb[tid / 49][tid % 49] = 0.f;
    for (int e = tid; e < 1392; e += 256) {     // zero halo borders only
        int c12 = e / 116, u = e % 116, idx;
        if (u < 30)      idx = u;                        // top row
        else if (u < 60) idx = 29 * 34 + (u - 30);       // bottom row
        else { int v = u - 60; idx = ((v >> 1) + 1) * 34 + (v & 1) * 29; }
        plane[c12][idx] = 0;
    }
    {   // 12 conv planes: one contiguous 18,816 B streak of uint4 (8 px each)
        const uint4* src = (const uint4*)(perm + ((size_t)b * 64 + g) * 12 * HWH);
        for (int e = tid; e < 1176; e += 256) {
            int c12 = e / 98, u = e % 98;
            uint4 q = src[e];
            ushort s8[8] = {(ushort)(q.x & 0xffff), (ushort)(q.x >> 16),
                            (ushort)(q.y & 0xffff), (ushort)(q.y >> 16),
                            (ushort)(q.z & 0xffff), (ushort)(q.z >> 16),
                            (ushort)(q.w & 0xffff), (ushort)(q.w >> 16)};
            int p = u * 8, y = p / 28, x = p - y * 28;
            int ry = y + 1, cx = x + 1;
            short* pl = &plane[c12][0];
#pragma unroll
            for (int t4 = 0; t4 < 8; ++t4) {
                pl[ry * 34 + cx] = (short)s8[t4];
                if (++cx == 29) { cx = 1; ++ry; }
            }
        }
    }
    for (int e = tid; e < 392; e += 256) {      // 4 v-planes for attention
        int oc = e / 98, u = e % 98;
        int c = 4 * g + oc;                     // v channel -> perm[b][c%64][8+c/64]
        const uint4* src = (const uint4*)(
            perm + (((size_t)b * 64 + (c & 63)) * 12 + 8 + (c >> 6)) * HWH);
        reinterpret_cast<uint4*>(&vatt[oc][0])[u] = src[u];
    }
    __syncthreads();

    // ---- phase B: attention window means (interior windows only) ----
    if (tid < 100) {
        int oc = tid / 25, w = tid % 25;
        int wi = w / 5 + 1, wj = w % 5 + 1;
        int r0 = 4 * wi - 4, c0 = 4 * wj - 4;
        float s = 0.f;
#pragma unroll
        for (int r = 0; r < 12; ++r) {
            const __hip_bfloat162* pv =
                (const __hip_bfloat162*)&vatt[oc][(r0 + r) * 28 + c0];
#pragma unroll
            for (int q = 0; q < 6; ++q) {
                float2 f = __bfloat1622float2(pv[q]);
                s += f.x + f.y;
            }
        }
        attb[oc][wi * 7 + wj] = s * (1.0f / 144.0f);
    }

    // ---- phase C: conv, f32x2 packed. Lanes consecutive in y, pitch 34
    //      shorts (bank stride 17, coprime 32 -> conflict-free).
    f32x2 acc2[4][2] = {};   // [oc][pair]: pair0=(px0,px1), pair1=(px2,px3)
    const int y = tid % 28, xs = tid / 28, x0 = xs * 4;
    if (tid < 196) {
#pragma unroll
        for (int c = 0; c < 12; ++c) {
            // rr2[dy][jp] = img cols (x0-1+2*jp, x0+2*jp): 6 taps per row
            f32x2 rr2[3][3], sh[3][2];
#pragma unroll
            for (int dy = 0; dy < 3; ++dy) {
                const uint* row = (const uint*)&plane[c][(y + dy) * 34 + x0];
#pragma unroll
                for (int jp = 0; jp < 3; ++jp) {
                    uint w = row[jp];
                    float2 f = __bfloat1622float2(*(const __hip_bfloat162*)&w);
                    rr2[dy][jp] = f32x2{f.x, f.y};
                }
                sh[dy][0] = f32x2{rr2[dy][0].y, rr2[dy][1].x};  // taps 1,2
                sh[dy][1] = f32x2{rr2[dy][1].y, rr2[dy][2].x};  // taps 3,4
            }
#pragma unroll
            for (int oc = 0; oc < 4; ++oc) {
                const float4* wr = reinterpret_cast<const float4*>(&w2s2[oc][c][0]);
                float4 wa = wr[0], wb = wr[1], wc = wr[2];
                const float wk[9] = {wa.x, wa.y, wa.z, wa.w, wb.x, wb.y, wb.z, wb.w, wc.x};
#pragma unroll
                for (int ky = 0; ky < 3; ++ky) {
                    f32x2 w0 = {wk[ky * 3 + 0], wk[ky * 3 + 0]};
                    f32x2 w1 = {wk[ky * 3 + 1], wk[ky * 3 + 1]};
                    f32x2 w2v = {wk[ky * 3 + 2], wk[ky * 3 + 2]};
                    acc2[oc][0] += w0 * rr2[ky][0];   // kx=0: taps 0,1
                    acc2[oc][1] += w0 * rr2[ky][1];   //       taps 2,3
                    acc2[oc][0] += w1 * sh[ky][0];    // kx=1: taps 1,2
                    acc2[oc][1] += w1 * sh[ky][1];    //       taps 3,4
                    acc2[oc][0] += w2v * rr2[ky][1];  // kx=2: taps 2,3
                    acc2[oc][1] += w2v * rr2[ky][2];  //       taps 4,5
                }
            }
        }
    }
    __syncthreads();

    // ---- phase D: combine + store ----
    if (tid < 196) {
        const float r1 = rate1[0], r2 = rate2[0];
        const int wi = y >> 2, wj = xs;
#pragma unroll
        for (int oc = 0; oc < 4; ++oc) {
            float av = attb[oc][wi * 7 + wj] * r1;
            float4 o;
            o.x = av + r2 * acc2[oc][0].x;
            o.y = av + r2 * acc2[oc][0].y;
            o.z = av + r2 * acc2[oc][1].x;
            o.w = av + r2 * acc2[oc][1].y;
            *reinterpret_cast<float4*>(
                &out[((size_t)(b * 256 + 4 * g + oc)) * HWH + y * 28 + x0]) = o;
        }
    }
}

// ---------------------------------------------------------------------------
extern "C" void kernel_launch(void* const* d_in, const int* in_sizes, int n_in,
                              void* d_out, int out_size, void* d_ws, size_t ws_size,
                              hipStream_t stream) {
    const float* x     = (const float*)d_in[0];
    const float* w1    = (const float*)d_in[1];
    const float* b1    = (const float*)d_in[2];
    const float* w2    = (const float*)d_in[3];
    const float* b2    = (const float*)d_in[4];
    const float* w3    = (const float*)d_in[5];
    const float* b3    = (const float*)d_in[6];
    const float* fc_w  = (const float*)d_in[7];
    const float* dep_w = (const float*)d_in[8];
    // d_in[9]/d_in[10] = rel_height/rel_width: provably dead (mask collapse)
    const float* rate1 = (const float*)d_in[11];
    const float* rate2 = (const float*)d_in[12];
    float* out = (float*)d_out;

    // workspace layout — identical to the passing R4/R6 builds.
    // perm = 64*64*12*784 elements * 2 B = 77,070,336 BYTES.
    char* wsb = (char*)d_ws;
    bf16*  perm    = (bf16*)wsb;                         // 77,070,336 B
    bf16*  xT      = (bf16*)(wsb + 77070336);            // 64*784*256*2 = 25,690,112 B
    bf16*  wbf     = (bf16*)(wsb + 102760448);           // 768*256*2    =    393,216 B
    float* W2      = (float*)(wsb + 103153664);          // 256*108*4    =    110,592 B
    float* biascat = (float*)(wsb + 103264256);          // 768*4        =      3,072 B

    fold_w2   <<<dim3(108),        dim3(256), 0, stream>>>(fc_w, dep_w, b1, b2, b3, W2, biascat);
    wprep     <<<dim3(768),        dim3(256), 0, stream>>>(w1, w2, w3, wbf);
    xpose     <<<dim3(25, 8, 64),  dim3(256), 0, stream>>>(x, xT);
    gemm_mfma2<<<dim3(1344),       dim3(256), 0, stream>>>(wbf, biascat, xT, perm);
    out_fused5<<<dim3(64, 64),     dim3(256), 0, stream>>>(perm, W2, rate1, rate2, out);
}